// Round 6
// baseline (29.458 us; speedup 1.0000x reference)
//
#include <hip/hip_runtime.h>
#include <math.h>

// RKN cell: B=4096, LOD=64, LSD=128, H=64, NB=15, NE=436 (band +-3)
#define O_PM   0
#define O_PCU  524288
#define O_PCL  786432
#define O_PCS  1048576
#define O_NM   1310720
#define O_NCU  1835008
#define O_NCL  2097152
#define O_NCS  2359296

__device__ __forceinline__ float rlane(float v, int l) {
    return __uint_as_float(__builtin_amdgcn_readlane(__float_as_uint(v), l));
}
__device__ __forceinline__ unsigned pk2(float a, float b) {   // 2xf32 -> 2xbf16 (RNE)
    unsigned ua = __float_as_uint(a), ub = __float_as_uint(b);
    ua += 0x7fffu + ((ua >> 16) & 1u);
    ub += 0x7fffu + ((ub >> 16) & 1u);
    return (ua >> 16) | (ub & 0xffff0000u);
}
__device__ __forceinline__ float lo16(unsigned w) { return __uint_as_float(w << 16); }
__device__ __forceinline__ float hi16(unsigned w) { return __uint_as_float(w & 0xffff0000u); }
__device__ __forceinline__ unsigned short tobf(float a) {
    unsigned ua = __float_as_uint(a);
    ua += 0x7fffu + ((ua >> 16) & 1u);
    return (unsigned short)(ua >> 16);
}
__device__ __forceinline__ float frombf(unsigned short u) {
    return __uint_as_float(((unsigned)u) << 16);
}
__device__ __forceinline__ float frcp(float x) { return __builtin_amdgcn_rcpf(x); }
__device__ __forceinline__ float ftanh(float x) {
    float e = __expf(2.f * x);
    return 1.f - 2.f * frcp(e + 1.f);
}

// 256 threads, 4 rows/block, 1024 blocks.
// LDS = 8000 words = 32000 B -> 5 blocks/CU (20 waves, 5 barrier domains).
// Register diet: basis bf16-packed 30 u32 held (not 60 f32); phase 3 in two
// e-passes with acc[4][4]; peak live ~85 VGPR -> no spills at the 128 cap.
//  [0,6656)  weights bf16 image: W1v[16k8][64j]u4 | W2v[8][64] | W3v[8][16]
//            UNION tmv bf16 [16 mr][436] (3488 words)
//  [6656,7168) pm_s [4][128] f32
//  [7168,7424) pcu_s; [7424,7680) pcl_s; [7680,7936) pcs_s   [4][64] each
//  [7936,8000) coef_s [4][16]
__global__ __launch_bounds__(256, 4)
void rkn_kernel(const float* __restrict__ prior_mean,
                const float* __restrict__ cov_u,
                const float* __restrict__ cov_l,
                const float* __restrict__ cov_s,
                const float* __restrict__ obs,
                const float* __restrict__ obs_var,
                const float* __restrict__ W1,
                const float* __restrict__ b1,
                const float* __restrict__ W2,
                const float* __restrict__ b2,
                const float* __restrict__ W3,
                const float* __restrict__ b3,
                const float* __restrict__ tm11b,
                const float* __restrict__ tm12b,
                const float* __restrict__ tm21b,
                const float* __restrict__ tm22b,
                const float* __restrict__ ltn,
                float* __restrict__ out)
{
    __shared__ __align__(16) unsigned smem[8000];
    uint4* lds4 = (uint4*)smem;
    uint4* W1v  = (uint4*)smem;              // [16 k8][64 j]
    uint4* W2v  = (uint4*)(smem + 4096);     // [8 k8][64 j]
    uint4* W3v  = (uint4*)(smem + 6144);     // [8 k8][16 j]
    unsigned short* tmv = (unsigned short*)smem;   // [16][436] bf16 (union)
    float* pm_s   = (float*)(smem + 6656);
    float* pcu_s  = (float*)(smem + 7168);
    float* pcl_s  = (float*)(smem + 7424);
    float* pcs_s  = (float*)(smem + 7680);
    float* coef_s = (float*)(smem + 7936);

    const int tid  = threadIdx.x;
    const int wid  = tid >> 6;          // wave = row within block (0..3)
    const int lane = tid & 63;
    const int row  = blockIdx.x * 4 + wid;
    const int jj   = lane & 15;

    // ---- per-row input loads (coalesced) ----
    const float cu   = cov_u[row * 64 + lane];
    const float cl   = cov_l[row * 64 + lane];
    const float cs   = cov_s[row * 64 + lane];
    const float ob   = obs[row * 64 + lane];
    const float ov   = obs_var[row * 64 + lane];
    const float pmu0 = prior_mean[row * 128 + lane];
    const float pml0 = prior_mean[row * 128 + 64 + lane];
    const float bias1 = b1[lane];
    const float bias2 = b2[lane];
    const float bias3 = (jj < 15) ? b3[jj] : 0.f;

    // ---- pass-0 basis (e0 = tid < 256 always active), packed to 30 u32 ----
    unsigned bas0[32];
#pragma unroll
    for (int m = 0; m < 4; ++m) {
        const float* bp = (m == 0) ? tm11b : (m == 1) ? tm12b : (m == 2) ? tm21b : tm22b;
#pragma unroll
        for (int k2 = 0; k2 < 8; ++k2) {
            const float lo = bp[(2 * k2) * 436 + tid];
            const float hi = (2 * k2 + 1 < 15) ? bp[(2 * k2 + 1) * 436 + tid] : 0.f;
            bas0[m * 8 + k2] = pk2(lo, hi);
        }
    }

    // ---- stage weight image: bf16-pack inline (1664 uint4, 7 iters) ----
#pragma unroll
    for (int it = 0; it < 7; ++it) {
        const int idx = tid + it * 256;
        if (idx < 1664) {
            uint4 v = make_uint4(0u, 0u, 0u, 0u);
            if (idx < 1024) {                 // W1
                const int j = idx & 63, k8 = idx >> 6;
                const float4* p = (const float4*)(W1 + j * 128 + k8 * 8);
                const float4 a = p[0], b = p[1];
                v = make_uint4(pk2(a.x, a.y), pk2(a.z, a.w), pk2(b.x, b.y), pk2(b.z, b.w));
            } else if (idx < 1536) {          // W2
                const int q = idx - 1024;
                const int j = q & 63, k8 = q >> 6;
                const float4* p = (const float4*)(W2 + j * 64 + k8 * 8);
                const float4 a = p[0], b = p[1];
                v = make_uint4(pk2(a.x, a.y), pk2(a.z, a.w), pk2(b.x, b.y), pk2(b.z, b.w));
            } else {                          // W3 (j=15 stays zero)
                const int q = idx - 1536;
                const int j = q & 15, k8 = q >> 4;
                if (j < 15) {
                    const float4* p = (const float4*)(W3 + j * 64 + k8 * 8);
                    const float4 a = p[0], b = p[1];
                    v = make_uint4(pk2(a.x, a.y), pk2(a.z, a.w), pk2(b.x, b.y), pk2(b.z, b.w));
                }
            }
            lds4[idx] = v;
        }
    }

    // softplus(trans noise), fast intrinsics
    const float tcu = __logf(__expf(ltn[lane]) + 1.f);
    const float tcl = __logf(__expf(ltn[64 + lane]) + 1.f);

    // ---- phase 1: Kalman update ----
    const float inv = frcp(cu + ov);
    const float qu  = cu * inv;
    const float ql  = cs * inv;
    const float res = ob - pmu0;
    const float pmu = pmu0 + qu * res;
    const float pml = pml0 + ql * res;
    const float cf  = 1.f - qu;
    const float pcu = cf * cu;
    const float pcl = cl - ql * cs;
    const float pcs = cf * cs;

    out[O_PM  + row * 128 + lane]      = pmu;
    out[O_PM  + row * 128 + 64 + lane] = pml;
    out[O_PCU + row * 64 + lane] = pcu;
    out[O_PCL + row * 64 + lane] = pcl;
    out[O_PCS + row * 64 + lane] = pcs;

    pm_s [wid * 128 + lane]      = pmu;
    pm_s [wid * 128 + 64 + lane] = pml;
    pcu_s[wid * 64 + lane] = pcu;
    pcl_s[wid * 64 + lane] = pcl;
    pcs_s[wid * 64 + lane] = pcs;

    __syncthreads();   // weights staged + row state visible

    // ---- phase 2: MLP (bf16x8 weight reads, readlane activation b'cast) ----
    float ac0 = bias1, ac1 = 0.f, ac2 = 0.f, ac3 = 0.f;
#pragma unroll
    for (int k8 = 0; k8 < 16; ++k8) {
        const uint4 wv = W1v[k8 * 64 + lane];
        const float src = (k8 < 8) ? pmu : pml;
        const int bl = (k8 & 7) * 8;
        ac0 += lo16(wv.x) * rlane(src, bl + 0);
        ac1 += hi16(wv.x) * rlane(src, bl + 1);
        ac2 += lo16(wv.y) * rlane(src, bl + 2);
        ac3 += hi16(wv.y) * rlane(src, bl + 3);
        ac0 += lo16(wv.z) * rlane(src, bl + 4);
        ac1 += hi16(wv.z) * rlane(src, bl + 5);
        ac2 += lo16(wv.w) * rlane(src, bl + 6);
        ac3 += hi16(wv.w) * rlane(src, bl + 7);
    }
    const float h1v = ftanh((ac0 + ac1) + (ac2 + ac3));

    ac0 = bias2; ac1 = 0.f; ac2 = 0.f; ac3 = 0.f;
#pragma unroll
    for (int k8 = 0; k8 < 8; ++k8) {
        const uint4 wv = W2v[k8 * 64 + lane];
        const int bl = k8 * 8;
        ac0 += lo16(wv.x) * rlane(h1v, bl + 0);
        ac1 += hi16(wv.x) * rlane(h1v, bl + 1);
        ac2 += lo16(wv.y) * rlane(h1v, bl + 2);
        ac3 += hi16(wv.y) * rlane(h1v, bl + 3);
        ac0 += lo16(wv.z) * rlane(h1v, bl + 4);
        ac1 += hi16(wv.z) * rlane(h1v, bl + 5);
        ac2 += lo16(wv.w) * rlane(h1v, bl + 6);
        ac3 += hi16(wv.w) * rlane(h1v, bl + 7);
    }
    const float h2v = ftanh((ac0 + ac1) + (ac2 + ac3));

    ac0 = bias3; ac1 = 0.f; ac2 = 0.f; ac3 = 0.f;
#pragma unroll
    for (int k8 = 0; k8 < 8; ++k8) {
        const uint4 wv = W3v[k8 * 16 + jj];
        const int bl = k8 * 8;
        ac0 += lo16(wv.x) * rlane(h2v, bl + 0);
        ac1 += hi16(wv.x) * rlane(h2v, bl + 1);
        ac2 += lo16(wv.y) * rlane(h2v, bl + 2);
        ac3 += hi16(wv.y) * rlane(h2v, bl + 3);
        ac0 += lo16(wv.z) * rlane(h2v, bl + 4);
        ac1 += hi16(wv.z) * rlane(h2v, bl + 5);
        ac2 += lo16(wv.w) * rlane(h2v, bl + 6);
        ac3 += hi16(wv.w) * rlane(h2v, bl + 7);
    }
    const float l3 = (ac0 + ac1) + (ac2 + ac3);   // logit jj lives in lane jj

    // ---- in-wave softmax (logit k in lane k, k<15) ----
    {
        float mx = rlane(l3, 0);
#pragma unroll
        for (int k = 1; k < 15; ++k) mx = fmaxf(mx, rlane(l3, k));
        const float ex = __expf(l3 - mx);
        float s = rlane(ex, 0);
#pragma unroll
        for (int k = 1; k < 15; ++k) s += rlane(ex, k);
        const float cval = ex * frcp(s);
        if (lane < 16) coef_s[wid * 16 + lane] = (lane < 15) ? cval : 0.f;
    }

    __syncthreads();   // coeffs visible; weight region now dead -> tmv reuse

    // ---- phase 3: tm[m][r][e] = sum_k coeff[r][k]*basis_m[k][e], 2 e-passes ----
    {
        const float cv0 = coef_s[lane];     // all 4 rows: (r,k)=(lane>>4,lane&15)

        // pass 0: e0 = tid (always active)
        float acc[4][4];
#pragma unroll
        for (int m = 0; m < 4; ++m)
#pragma unroll
            for (int r = 0; r < 4; ++r) acc[m][r] = 0.f;
#pragma unroll
        for (int k2 = 0; k2 < 8; ++k2) {
#pragma unroll
            for (int kk = 0; kk < 2; ++kk) {
                const int k = 2 * k2 + kk;
                if (k < 15) {
                    const float c0 = rlane(cv0, k);
                    const float c1 = rlane(cv0, 16 + k);
                    const float c2 = rlane(cv0, 32 + k);
                    const float c3 = rlane(cv0, 48 + k);
#pragma unroll
                    for (int m = 0; m < 4; ++m) {
                        const float b = kk ? hi16(bas0[m * 8 + k2]) : lo16(bas0[m * 8 + k2]);
                        acc[m][0] += c0 * b;
                        acc[m][1] += c1 * b;
                        acc[m][2] += c2 * b;
                        acc[m][3] += c3 * b;
                    }
                }
            }
        }
#pragma unroll
        for (int m = 0; m < 4; ++m)
#pragma unroll
            for (int r = 0; r < 4; ++r)
                tmv[(m * 4 + r) * 436 + tid] = tobf(acc[m][r]);

        // pass 1: e1 = tid + 256 (active if < 436); load+pack basis now
        const int  e1   = tid + 256;
        const bool act1 = (e1 < 436);
        const int  e1c  = act1 ? e1 : 435;
        unsigned bas1[32];
#pragma unroll
        for (int m = 0; m < 4; ++m) {
            const float* bp = (m == 0) ? tm11b : (m == 1) ? tm12b : (m == 2) ? tm21b : tm22b;
#pragma unroll
            for (int k2 = 0; k2 < 8; ++k2) {
                const float lo = bp[(2 * k2) * 436 + e1c];
                const float hi = (2 * k2 + 1 < 15) ? bp[(2 * k2 + 1) * 436 + e1c] : 0.f;
                bas1[m * 8 + k2] = pk2(lo, hi);
            }
        }
#pragma unroll
        for (int m = 0; m < 4; ++m)
#pragma unroll
            for (int r = 0; r < 4; ++r) acc[m][r] = 0.f;
#pragma unroll
        for (int k2 = 0; k2 < 8; ++k2) {
#pragma unroll
            for (int kk = 0; kk < 2; ++kk) {
                const int k = 2 * k2 + kk;
                if (k < 15) {
                    const float c0 = rlane(cv0, k);
                    const float c1 = rlane(cv0, 16 + k);
                    const float c2 = rlane(cv0, 32 + k);
                    const float c3 = rlane(cv0, 48 + k);
#pragma unroll
                    for (int m = 0; m < 4; ++m) {
                        const float b = kk ? hi16(bas1[m * 8 + k2]) : lo16(bas1[m * 8 + k2]);
                        acc[m][0] += c0 * b;
                        acc[m][1] += c1 * b;
                        acc[m][2] += c2 * b;
                        acc[m][3] += c3 * b;
                    }
                }
            }
        }
        if (act1) {
#pragma unroll
            for (int m = 0; m < 4; ++m)
#pragma unroll
                for (int r = 0; r < 4; ++r)
                    tmv[(m * 4 + r) * 436 + e1] = tobf(acc[m][r]);
        }
    }

    __syncthreads();   // tm visible

    // ---- phase 4: banded mat-vec combos (wave=row, lane i=output dim) ----
    {
        const int i   = lane;
        const int jlo = (i - 3 > 0) ? (i - 3) : 0;
        const int ne  = ((i + 3 < 63) ? (i + 3) : 63) - jlo + 1;
        const int base = (i < 4)  ? (i * (i + 7)) / 2
                       : (i <= 61) ? (7 * i - 6)
                       : (i == 62) ? 427 : 432;

        float nmu = 0.f, nml = 0.f, ncu = 0.f, ncl = 0.f, ncs = 0.f;
#pragma unroll
        for (int d = 0; d < 7; ++d) {
            if (d < ne) {
                const int j  = jlo + d;
                const int eI = base + d;
                float t11 = frombf(tmv[(0 * 4 + wid) * 436 + eI]);
                float t12 = frombf(tmv[(1 * 4 + wid) * 436 + eI]);
                float t21 = frombf(tmv[(2 * 4 + wid) * 436 + eI]);
                float t22 = frombf(tmv[(3 * 4 + wid) * 436 + eI]);
                if (j == i) { t11 += 1.f; t22 += 1.f; }
                const float mu  = pm_s[wid * 128 + j];
                const float ml  = pm_s[wid * 128 + 64 + j];
                const float vcu = pcu_s[wid * 64 + j];
                const float vcl = pcl_s[wid * 64 + j];
                const float vcs = pcs_s[wid * 64 + j];
                nmu += t11 * mu + t12 * ml;
                nml += t21 * mu + t22 * ml;
                ncu += t11 * t11 * vcu + 2.f * t11 * t12 * vcs + t12 * t12 * vcl;
                ncl += t21 * t21 * vcu + 2.f * t21 * t22 * vcs + t22 * t22 * vcl;
                ncs += t21 * t11 * vcu + (t22 * t11 + t21 * t12) * vcs + t22 * t12 * vcl;
            }
        }
        out[O_NM  + row * 128 + i]      = nmu;
        out[O_NM  + row * 128 + 64 + i] = nml;
        out[O_NCU + row * 64 + i] = ncu + tcu;
        out[O_NCL + row * 64 + i] = ncl + tcl;
        out[O_NCS + row * 64 + i] = ncs;
    }
}

extern "C" void kernel_launch(void* const* d_in, const int* in_sizes, int n_in,
                              void* d_out, int out_size, void* d_ws, size_t ws_size,
                              hipStream_t stream) {
    rkn_kernel<<<dim3(1024), dim3(256), 0, stream>>>(
        (const float*)d_in[0],  // prior_mean
        (const float*)d_in[1],  // cov_u
        (const float*)d_in[2],  // cov_l
        (const float*)d_in[3],  // cov_s
        (const float*)d_in[4],  // obs
        (const float*)d_in[5],  // obs_var
        (const float*)d_in[6],  // W1
        (const float*)d_in[7],  // b1
        (const float*)d_in[8],  // W2
        (const float*)d_in[9],  // b2
        (const float*)d_in[10], // W3
        (const float*)d_in[11], // b3
        (const float*)d_in[12], // tm11_basis
        (const float*)d_in[13], // tm12_basis
        (const float*)d_in[14], // tm21_basis
        (const float*)d_in[15], // tm22_basis
        (const float*)d_in[16], // log_trans_noise
        (float*)d_out);
}